// Round 8
// baseline (125.059 us; speedup 1.0000x reference)
//
#include <hip/hip_runtime.h>
#include <stdint.h>

#define N_NODES 50000
#define N_EDGES 600000
#define D       128
#define EPS     1e-5f
#define HG      32          // slices per index array (600000/32 = 18750 < 65536)
#define NWORDS  25000       // 50000 u16 counters packed in u32 words

typedef __attribute__((ext_vector_type(8))) short bf16x8;   // 8 bf16 = 4 VGPR
typedef __attribute__((ext_vector_type(4))) float f32x4;    // MFMA acc

__device__ __forceinline__ unsigned short f2bf(float x) {   // RNE f32->bf16
    unsigned int u = __float_as_uint(x);
    return (unsigned short)((u + 0x7fffu + ((u >> 16) & 1u)) >> 16);
}

__device__ __forceinline__ int load_idx(const void* e, long long i, int is64) {
    return is64 ? (int)((const long long*)e)[i] : ((const int*)e)[i];
}

// in-block edge dtype detect (wave 0): int64 => high words all zero
__device__ __forceinline__ int block_detect64(const unsigned int* eraw, int* sflag) {
    if (threadIdx.x < 64) {
        unsigned long long nz = __ballot(eraw[2 * threadIdx.x + 1] != 0u);
        if (threadIdx.x == 0) *sflag = (nz == 0ull) ? 1 : 0;
    }
    __syncthreads();
    return *sflag;
}

// ---------------------------------------------------------------------------
// degree histograms in LDS (zero global atomics). 2*HG blocks x 1024 thr;
// blocks [0,HG) count src, [HG,2HG) count dst, each over an 18750-edge slice.
// Block 0 additionally casts W f32 -> bf16 (fused to save a launch).
// ---------------------------------------------------------------------------
__global__ __launch_bounds__(1024) void hist_kernel(const unsigned int* __restrict__ eraw,
                                                    unsigned int* __restrict__ partials,
                                                    const float2* __restrict__ W2,
                                                    unsigned int* __restrict__ Wb) {
    __shared__ unsigned int lhist[NWORDS];
    __shared__ int sflag;
    int t = threadIdx.x;
    int which = blockIdx.x >= HG;
    int b     = blockIdx.x & (HG - 1);
    for (int i = t; i < NWORDS; i += 1024) lhist[i] = 0u;
    int is64 = block_detect64(eraw, &sflag);   // includes __syncthreads
    const int per = N_EDGES / HG;
    int lo = b * per, hi = lo + per;
    long long base = which ? (long long)N_EDGES : 0ll;
    for (int i = lo + t; i < hi; i += 1024) {
        int v = load_idx(eraw, base + i, is64);
        atomicAdd(&lhist[v >> 1], (v & 1) ? (1u << 16) : 1u);
    }
    __syncthreads();
    unsigned int* dst = partials + (size_t)blockIdx.x * NWORDS;
    for (int i = t; i < NWORDS; i += 1024) dst[i] = lhist[i];
    if (blockIdx.x == 0) {
        for (int i = t; i < 128 * 128; i += 1024) {
            float2 w = W2[i];
            Wb[i] = (unsigned int)f2bf(w.x) | ((unsigned int)f2bf(w.y) << 16);
        }
    }
}

// ---------------------------------------------------------------------------
// sum per-slice partials -> deg_in (u32) + inv_out/inv_in = rsqrt(max(deg,1))
// ---------------------------------------------------------------------------
__global__ __launch_bounds__(256) void deg_reduce(const unsigned int* __restrict__ partials,
                                                  unsigned int* __restrict__ deg_in,
                                                  float* __restrict__ inv_out,
                                                  float* __restrict__ inv_in) {
    int w = blockIdx.x * 256 + threadIdx.x;
    if (w >= NWORDS) return;
    unsigned int o0 = 0, o1 = 0, d0 = 0, d1 = 0;
    for (int b = 0; b < HG; ++b) {
        unsigned int p = partials[(size_t)b * NWORDS + w];
        o0 += p & 0xffffu; o1 += p >> 16;
    }
    for (int b = 0; b < HG; ++b) {
        unsigned int p = partials[(size_t)(HG + b) * NWORDS + w];
        d0 += p & 0xffffu; d1 += p >> 16;
    }
    deg_in[2 * w]     = d0;
    deg_in[2 * w + 1] = d1;
    inv_out[2 * w]     = rsqrtf((float)(o0 > 1u ? o0 : 1u));
    inv_out[2 * w + 1] = rsqrtf((float)(o1 > 1u ? o1 : 1u));
    inv_in[2 * w]      = rsqrtf((float)(d0 > 1u ? d0 : 1u));
    inv_in[2 * w + 1]  = rsqrtf((float)(d1 > 1u ? d1 : 1u));
}

// ---------------------------------------------------------------------------
// two-phase multi-block exclusive scan of deg_in -> row_start
// ---------------------------------------------------------------------------
__global__ __launch_bounds__(1024) void scan1(const unsigned int* __restrict__ deg,
                                              unsigned int* __restrict__ row_start,
                                              unsigned int* __restrict__ partials) {
    __shared__ unsigned int wsum[16];
    int t = threadIdx.x, lane = t & 63, w = t >> 6;
    int i = blockIdx.x * 1024 + t;
    unsigned int v = (i < N_NODES) ? deg[i] : 0u;
    unsigned int x = v;
    #pragma unroll
    for (int off = 1; off < 64; off <<= 1) {
        unsigned int y = __shfl_up(x, off, 64);
        if (lane >= off) x += y;
    }
    if (lane == 63) wsum[w] = x;
    __syncthreads();
    if (w == 0) {
        unsigned int s = (lane < 16) ? wsum[lane] : 0u;
        #pragma unroll
        for (int off = 1; off < 16; off <<= 1) {
            unsigned int y = __shfl_up(s, off, 64);
            if (lane >= off) s += y;
        }
        if (lane < 16) wsum[lane] = s;
    }
    __syncthreads();
    unsigned int excl = (w ? wsum[w - 1] : 0u) + x - v;
    if (i < N_NODES) row_start[i] = excl;
    if (t == 1023) partials[blockIdx.x] = wsum[15];
}

__global__ __launch_bounds__(1024) void scan2(const unsigned int* __restrict__ partials,
                                              unsigned int* __restrict__ row_start) {
    __shared__ unsigned int soff;
    int t = threadIdx.x, b = blockIdx.x;
    if (t < 64) {
        unsigned int p = (t < b) ? partials[t] : 0u;   // gridDim 49 <= 64
        #pragma unroll
        for (int off = 32; off; off >>= 1) p += __shfl_xor(p, off, 64);
        if (t == 0) soff = p;
    }
    __syncthreads();
    int i = b * 1024 + t;
    if (i < N_NODES) row_start[i] += soff;
    if (b == 0 && t == 0) row_start[N_NODES] = N_EDGES;
}

// ---------------------------------------------------------------------------
// pre[b][v] = row_start[v] + sum_{b'<b} dst_partial[b'][v]
// ---------------------------------------------------------------------------
__global__ __launch_bounds__(256) void prefix_kernel(const unsigned int* __restrict__ partials,
                                                     const unsigned int* __restrict__ row_start,
                                                     unsigned int* __restrict__ pre) {
    int w = blockIdx.x * 256 + threadIdx.x;
    if (w >= NWORDS) return;
    unsigned int run0 = row_start[2 * w], run1 = row_start[2 * w + 1];
    for (int b = 0; b < HG; ++b) {
        pre[(size_t)b * N_NODES + 2 * w]     = run0;
        pre[(size_t)b * N_NODES + 2 * w + 1] = run1;
        unsigned int p = partials[(size_t)(HG + b) * NWORDS + w];
        run0 += p & 0xffffu; run1 += p >> 16;
    }
}

// ---------------------------------------------------------------------------
// atomic-free CSR fill: block b handles slice b with LDS packed-u16 cursors;
// csr_src[pre[b][d] + local_pos] = s
// ---------------------------------------------------------------------------
__global__ __launch_bounds__(1024) void fill_kernel(const unsigned int* __restrict__ eraw,
                                                    const unsigned int* __restrict__ pre,
                                                    unsigned int* __restrict__ csr_src) {
    __shared__ unsigned int lcur[NWORDS];
    __shared__ int sflag;
    int t = threadIdx.x, b = blockIdx.x;
    for (int i = t; i < NWORDS; i += 1024) lcur[i] = 0u;
    int is64 = block_detect64(eraw, &sflag);
    const int per = N_EDGES / HG;
    int lo = b * per, hi = lo + per;
    const unsigned int* preb = pre + (size_t)b * N_NODES;
    for (int i = lo + t; i < hi; i += 1024) {
        int s = load_idx(eraw, i, is64);
        int d = load_idx(eraw, (long long)N_EDGES + i, is64);
        unsigned int old = atomicAdd(&lcur[d >> 1], (d & 1) ? (1u << 16) : 1u);
        unsigned int pl = (d & 1) ? (old >> 16) : (old & 0xffffu);
        csr_src[preb[d] + pl] = (unsigned int)s;
    }
}

// ---------------------------------------------------------------------------
// LayerNorm -> bf16 packed pairs
// ---------------------------------------------------------------------------
__global__ __launch_bounds__(256) void ln_kernel(const float2* __restrict__ h2,
                                                 const float2* __restrict__ g2,
                                                 const float2* __restrict__ b2,
                                                 unsigned int* __restrict__ hnb) {
    int wid  = threadIdx.x >> 6;
    int lane = threadIdx.x & 63;
    int row  = blockIdx.x * 4 + wid;
    if (row >= N_NODES) return;
    float2 v = h2[(size_t)row * 64 + lane];
    float s  = v.x + v.y;
    float ss = v.x * v.x + v.y * v.y;
    #pragma unroll
    for (int off = 32; off; off >>= 1) {
        s  += __shfl_xor(s,  off, 64);
        ss += __shfl_xor(ss, off, 64);
    }
    float mu  = s * (1.0f / D);
    float var = ss * (1.0f / D) - mu * mu;
    float rs  = rsqrtf(var + EPS);
    float2 g = g2[lane], b = b2[lane];
    float y0 = (v.x - mu) * rs * g.x + b.x;
    float y1 = (v.y - mu) * rs * g.y + b.y;
    hnb[(size_t)row * 64 + lane] = (unsigned int)f2bf(y0) | ((unsigned int)f2bf(y1) << 16);
}

// ---------------------------------------------------------------------------
// aggregation: one wave per dst row; 4 x 16-lane groups process 4 edges
// concurrently, 16 B (8 features) per lane; cross-group shfl reduce at end.
// (proven round-6 configuration)
// ---------------------------------------------------------------------------
__global__ __launch_bounds__(256) void agg_kernel(const unsigned int* __restrict__ hnb,
                                                  const float* __restrict__ inv_out,
                                                  const float* __restrict__ inv_in,
                                                  const unsigned int* __restrict__ row_start,
                                                  const unsigned int* __restrict__ csr_src,
                                                  unsigned int* __restrict__ aggb) {
    int wid  = threadIdx.x >> 6;
    int lane = threadIdx.x & 63;
    int row  = blockIdx.x * 4 + wid;
    if (row >= N_NODES) return;
    int g = lane >> 4, gl = lane & 15;
    unsigned int e0 = row_start[row], e1 = row_start[row + 1];
    float acc[8];
    #pragma unroll
    for (int j = 0; j < 8; ++j) acc[j] = 0.0f;

    unsigned int e = e0;
    while (e < e1) {
        unsigned int cnt = e1 - e;
        if (cnt > 64u) cnt = 64u;
        int sl = (lane < (int)cnt) ? (int)csr_src[e + lane] : 0;
        int nit = ((int)cnt + 3) >> 2;
        for (int it = 0; it < nit; ++it) {
            int idx = it * 4 + g;
            int s = __shfl(sl, idx, 64);       // per-lane src (uniform in group)
            if (idx < (int)cnt) {
                float sc = inv_out[s];
                uint4 v = *(const uint4*)(hnb + (size_t)s * 64 + gl * 4);
                acc[0] = fmaf(__uint_as_float(v.x << 16),          sc, acc[0]);
                acc[1] = fmaf(__uint_as_float(v.x & 0xffff0000u),  sc, acc[1]);
                acc[2] = fmaf(__uint_as_float(v.y << 16),          sc, acc[2]);
                acc[3] = fmaf(__uint_as_float(v.y & 0xffff0000u),  sc, acc[3]);
                acc[4] = fmaf(__uint_as_float(v.z << 16),          sc, acc[4]);
                acc[5] = fmaf(__uint_as_float(v.z & 0xffff0000u),  sc, acc[5]);
                acc[6] = fmaf(__uint_as_float(v.w << 16),          sc, acc[6]);
                acc[7] = fmaf(__uint_as_float(v.w & 0xffff0000u),  sc, acc[7]);
            }
        }
        e += cnt;
    }
    // combine the 4 groups (lanes with equal gl)
    #pragma unroll
    for (int j = 0; j < 8; ++j) {
        acc[j] += __shfl_xor(acc[j], 16, 64);
        acc[j] += __shfl_xor(acc[j], 32, 64);
    }
    if (g == 0) {
        float ii = inv_in[row];
        uint4 o;
        o.x = (unsigned int)f2bf(acc[0] * ii) | ((unsigned int)f2bf(acc[1] * ii) << 16);
        o.y = (unsigned int)f2bf(acc[2] * ii) | ((unsigned int)f2bf(acc[3] * ii) << 16);
        o.z = (unsigned int)f2bf(acc[4] * ii) | ((unsigned int)f2bf(acc[5] * ii) << 16);
        o.w = (unsigned int)f2bf(acc[6] * ii) | ((unsigned int)f2bf(acc[7] * ii) << 16);
        *(uint4*)(aggb + (size_t)row * 64 + gl * 4) = o;
    }
}

// ---------------------------------------------------------------------------
// MFMA GEMM: out[50000][128] = cat([hn|agg]) @ W^T + b
// ---------------------------------------------------------------------------
__global__ __launch_bounds__(256) void gemm_kernel(const unsigned short* __restrict__ hnb,
                                                   const unsigned short* __restrict__ aggb,
                                                   const unsigned short* __restrict__ Wb,
                                                   const float* __restrict__ bias,
                                                   float* __restrict__ out) {
    __shared__ unsigned short wlds[128 * 264];
    int t = threadIdx.x;
    {
        int j = t >> 1, half = t & 1;
        const uint4* src = (const uint4*)(Wb + (size_t)j * 256 + half * 128);
        uint4* dst = (uint4*)(wlds + j * 264 + half * 128);
        #pragma unroll
        for (int i = 0; i < 16; ++i) dst[i] = src[i];
    }
    __syncthreads();

    int w = t >> 6, lane = t & 63;
    int rbase = blockIdx.x * 64 + w * 16;
    if (rbase >= N_NODES) return;
    int lrow = lane & 15, lhi = lane >> 4;

    bf16x8 a[8];
    const unsigned short* hrow = hnb + (size_t)(rbase + lrow) * 128 + lhi * 8;
    const unsigned short* arow = aggb + (size_t)(rbase + lrow) * 128 + lhi * 8;
    #pragma unroll
    for (int kc = 0; kc < 4; ++kc) a[kc]     = *(const bf16x8*)(hrow + kc * 32);
    #pragma unroll
    for (int kc = 0; kc < 4; ++kc) a[4 + kc] = *(const bf16x8*)(arow + kc * 32);

    f32x4 acc[8];
    #pragma unroll
    for (int ct = 0; ct < 8; ++ct) acc[ct] = (f32x4){0.f, 0.f, 0.f, 0.f};

    #pragma unroll
    for (int ct = 0; ct < 8; ++ct) {
        const unsigned short* bb = wlds + (ct * 16 + lrow) * 264 + lhi * 8;
        #pragma unroll
        for (int kc = 0; kc < 8; ++kc) {
            bf16x8 bfrag = *(const bf16x8*)(bb + kc * 32);
            acc[ct] = __builtin_amdgcn_mfma_f32_16x16x32_bf16(a[kc], bfrag, acc[ct], 0, 0, 0);
        }
    }

    #pragma unroll
    for (int ct = 0; ct < 8; ++ct) {
        int col = ct * 16 + lrow;
        float bv = bias[col];
        #pragma unroll
        for (int i = 0; i < 4; ++i) {
            int row = rbase + lhi * 4 + i;
            out[(size_t)row * 128 + col] = acc[ct][i] + bv;
        }
    }
}

// ---------------------------------------------------------------------------
extern "C" void kernel_launch(void* const* d_in, const int* in_sizes, int n_in,
                              void* d_out, int out_size, void* d_ws, size_t ws_size,
                              hipStream_t stream) {
    const float* h     = (const float*)d_in[0];
    const unsigned int* eraw = (const unsigned int*)d_in[1];
    const float* gamma = (const float*)d_in[2];
    const float* beta  = (const float*)d_in[3];
    const float* W     = (const float*)d_in[4];
    const float* bias  = (const float*)d_in[5];
    float* out = (float*)d_out;

    char* ws = (char*)d_ws;
    size_t off = 0;
    auto alloc = [&](size_t bytes) { size_t o = off; off += (bytes + 255) & ~(size_t)255; return o; };
    unsigned int* hpart     = (unsigned int*)(ws + alloc((size_t)2 * HG * NWORDS * 4)); // 6.4 MB
    unsigned int* pre       = (unsigned int*)(ws + alloc((size_t)HG * N_NODES * 4));    // 6.4 MB
    unsigned int* deg_in    = (unsigned int*)(ws + alloc((size_t)N_NODES * 4));
    float*        inv_out   = (float*)(ws + alloc((size_t)N_NODES * 4));
    float*        inv_in    = (float*)(ws + alloc((size_t)N_NODES * 4));
    unsigned int* row_start = (unsigned int*)(ws + alloc((size_t)(N_NODES + 1) * 4));
    unsigned int* spart     = (unsigned int*)(ws + alloc(64 * 4));
    unsigned int* Wb        = (unsigned int*)(ws + alloc((size_t)128 * 256 * 2));
    unsigned int* csr_src   = (unsigned int*)(ws + alloc((size_t)N_EDGES * 4));
    unsigned int* hnb       = (unsigned int*)(ws + alloc((size_t)N_NODES * D * 2));
    unsigned int* aggb      = (unsigned int*)(ws + alloc((size_t)N_NODES * D * 2));

    hist_kernel<<<2 * HG, 1024, 0, stream>>>(eraw, hpart, (const float2*)W, Wb);
    ln_kernel<<<(N_NODES + 3) / 4, 256, 0, stream>>>((const float2*)h, (const float2*)gamma,
                                                     (const float2*)beta, hnb);
    deg_reduce<<<(NWORDS + 255) / 256, 256, 0, stream>>>(hpart, deg_in, inv_out, inv_in);
    scan1<<<(N_NODES + 1023) / 1024, 1024, 0, stream>>>(deg_in, row_start, spart);
    scan2<<<(N_NODES + 1023) / 1024, 1024, 0, stream>>>(spart, row_start);
    prefix_kernel<<<(NWORDS + 255) / 256, 256, 0, stream>>>(hpart, row_start, pre);
    fill_kernel<<<HG, 1024, 0, stream>>>(eraw, pre, csr_src);
    agg_kernel<<<(N_NODES + 3) / 4, 256, 0, stream>>>(hnb, inv_out, inv_in, row_start,
                                                      csr_src, aggb);
    gemm_kernel<<<(N_NODES + 63) / 64, 256, 0, stream>>>((const unsigned short*)hnb,
                                                         (const unsigned short*)aggb,
                                                         (const unsigned short*)Wb,
                                                         bias, out);
}

// Round 9
// 108.096 us; speedup vs baseline: 1.1569x; 1.1569x over previous
//
#include <hip/hip_runtime.h>
#include <stdint.h>

#define N_NODES 50000
#define N_EDGES 600000
#define D       128
#define EPS     1e-5f
#define HG      128         // slices per index array; per-slice <= 4688 edges
#define PER     ((N_EDGES + HG - 1) / HG)   // 4688
#define NWORDS  25000       // 50000 u16 counters packed in u32 words

typedef __attribute__((ext_vector_type(8))) short bf16x8;   // 8 bf16 = 4 VGPR
typedef __attribute__((ext_vector_type(4))) float f32x4;    // MFMA acc

__device__ __forceinline__ unsigned short f2bf(float x) {   // RNE f32->bf16
    unsigned int u = __float_as_uint(x);
    return (unsigned short)((u + 0x7fffu + ((u >> 16) & 1u)) >> 16);
}

__device__ __forceinline__ int load_idx(const void* e, long long i, int is64) {
    return is64 ? (int)((const long long*)e)[i] : ((const int*)e)[i];
}

// in-block edge dtype detect (wave 0): int64 => high words all zero
__device__ __forceinline__ int block_detect64(const unsigned int* eraw, int* sflag) {
    if (threadIdx.x < 64) {
        unsigned long long nz = __ballot(eraw[2 * threadIdx.x + 1] != 0u);
        if (threadIdx.x == 0) *sflag = (nz == 0ull) ? 1 : 0;
    }
    __syncthreads();
    return *sflag;
}

// ---------------------------------------------------------------------------
// degree histograms in LDS (zero global atomics). 2*HG blocks x 1024 thr;
// blocks [0,HG) count src, [HG,2HG) count dst, each over a <=4688-edge slice.
// Block 0 additionally casts W f32 -> bf16.
// ---------------------------------------------------------------------------
__global__ __launch_bounds__(1024) void hist_kernel(const unsigned int* __restrict__ eraw,
                                                    unsigned int* __restrict__ partials,
                                                    const float2* __restrict__ W2,
                                                    unsigned int* __restrict__ Wb) {
    __shared__ unsigned int lhist[NWORDS];
    __shared__ int sflag;
    int t = threadIdx.x;
    int which = blockIdx.x >= HG;
    int b     = blockIdx.x - (which ? HG : 0);
    for (int i = t; i < NWORDS; i += 1024) lhist[i] = 0u;
    int is64 = block_detect64(eraw, &sflag);   // includes __syncthreads
    int lo = b * PER;
    int hi = lo + PER; if (hi > N_EDGES) hi = N_EDGES;
    long long base = which ? (long long)N_EDGES : 0ll;
    for (int i = lo + t; i < hi; i += 1024) {
        int v = load_idx(eraw, base + i, is64);
        atomicAdd(&lhist[v >> 1], (v & 1) ? (1u << 16) : 1u);
    }
    __syncthreads();
    unsigned int* dst = partials + (size_t)blockIdx.x * NWORDS;
    for (int i = t; i < NWORDS; i += 1024) dst[i] = lhist[i];
    if (blockIdx.x == 0) {
        for (int i = t; i < 128 * 128; i += 1024) {
            float2 w = W2[i];
            Wb[i] = (unsigned int)f2bf(w.x) | ((unsigned int)f2bf(w.y) << 16);
        }
    }
}

// ---------------------------------------------------------------------------
// fused reduce + per-slice prefix. One thread per packed word (2 nodes):
//   - sum src partials -> inv_out
//   - walk dst partials: pre16[b][w] = packed slice-local exclusive prefix
//     (fits u16: <= node in-degree, ~<=50 for this input), accumulate deg_in
//   - emit deg_in (u32 for scan) + inv_in
// ---------------------------------------------------------------------------
__global__ __launch_bounds__(256) void reduce_prefix(const unsigned int* __restrict__ partials,
                                                     unsigned int* __restrict__ deg_in,
                                                     float* __restrict__ inv_out,
                                                     float* __restrict__ inv_in,
                                                     unsigned int* __restrict__ pre16) {
    int w = blockIdx.x * 256 + threadIdx.x;
    if (w >= NWORDS) return;
    unsigned int o0 = 0, o1 = 0;
    for (int b = 0; b < HG; ++b) {
        unsigned int p = partials[(size_t)b * NWORDS + w];
        o0 += p & 0xffffu; o1 += p >> 16;
    }
    unsigned int run0 = 0, run1 = 0;
    for (int b = 0; b < HG; ++b) {
        pre16[(size_t)b * NWORDS + w] = run0 | (run1 << 16);
        unsigned int p = partials[(size_t)(HG + b) * NWORDS + w];
        run0 += p & 0xffffu; run1 += p >> 16;
    }
    deg_in[2 * w]     = run0;
    deg_in[2 * w + 1] = run1;
    inv_out[2 * w]     = rsqrtf((float)(o0 > 1u ? o0 : 1u));
    inv_out[2 * w + 1] = rsqrtf((float)(o1 > 1u ? o1 : 1u));
    inv_in[2 * w]      = rsqrtf((float)(run0 > 1u ? run0 : 1u));
    inv_in[2 * w + 1]  = rsqrtf((float)(run1 > 1u ? run1 : 1u));
}

// ---------------------------------------------------------------------------
// two-phase multi-block exclusive scan of deg_in -> row_start
// ---------------------------------------------------------------------------
__global__ __launch_bounds__(1024) void scan1(const unsigned int* __restrict__ deg,
                                              unsigned int* __restrict__ row_start,
                                              unsigned int* __restrict__ partials) {
    __shared__ unsigned int wsum[16];
    int t = threadIdx.x, lane = t & 63, w = t >> 6;
    int i = blockIdx.x * 1024 + t;
    unsigned int v = (i < N_NODES) ? deg[i] : 0u;
    unsigned int x = v;
    #pragma unroll
    for (int off = 1; off < 64; off <<= 1) {
        unsigned int y = __shfl_up(x, off, 64);
        if (lane >= off) x += y;
    }
    if (lane == 63) wsum[w] = x;
    __syncthreads();
    if (w == 0) {
        unsigned int s = (lane < 16) ? wsum[lane] : 0u;
        #pragma unroll
        for (int off = 1; off < 16; off <<= 1) {
            unsigned int y = __shfl_up(s, off, 64);
            if (lane >= off) s += y;
        }
        if (lane < 16) wsum[lane] = s;
    }
    __syncthreads();
    unsigned int excl = (w ? wsum[w - 1] : 0u) + x - v;
    if (i < N_NODES) row_start[i] = excl;
    if (t == 1023) partials[blockIdx.x] = wsum[15];
}

__global__ __launch_bounds__(1024) void scan2(const unsigned int* __restrict__ partials,
                                              unsigned int* __restrict__ row_start) {
    __shared__ unsigned int soff;
    int t = threadIdx.x, b = blockIdx.x;
    if (t < 64) {
        unsigned int p = (t < b) ? partials[t] : 0u;   // gridDim 49 <= 64
        #pragma unroll
        for (int off = 32; off; off >>= 1) p += __shfl_xor(p, off, 64);
        if (t == 0) soff = p;
    }
    __syncthreads();
    int i = b * 1024 + t;
    if (i < N_NODES) row_start[i] += soff;
    if (b == 0 && t == 0) row_start[N_NODES] = N_EDGES;
}

// ---------------------------------------------------------------------------
// atomic-free CSR fill: block b = slice b, LDS packed-u16 cursors.
// csr16[row_start[d] + pre16half + local_pos] = (u16)src
// ---------------------------------------------------------------------------
__global__ __launch_bounds__(1024) void fill_kernel(const unsigned int* __restrict__ eraw,
                                                    const unsigned int* __restrict__ pre16,
                                                    const unsigned int* __restrict__ row_start,
                                                    unsigned short* __restrict__ csr16) {
    __shared__ unsigned int lcur[NWORDS];
    __shared__ int sflag;
    int t = threadIdx.x, b = blockIdx.x;
    for (int i = t; i < NWORDS; i += 1024) lcur[i] = 0u;
    int is64 = block_detect64(eraw, &sflag);
    int lo = b * PER;
    int hi = lo + PER; if (hi > N_EDGES) hi = N_EDGES;
    const unsigned int* preb = pre16 + (size_t)b * NWORDS;
    for (int i = lo + t; i < hi; i += 1024) {
        int s = load_idx(eraw, i, is64);
        int d = load_idx(eraw, (long long)N_EDGES + i, is64);
        unsigned int old = atomicAdd(&lcur[d >> 1], (d & 1) ? (1u << 16) : 1u);
        unsigned int pl  = (d & 1) ? (old >> 16) : (old & 0xffffu);
        unsigned int pw  = preb[d >> 1];
        unsigned int pv  = (d & 1) ? (pw >> 16) : (pw & 0xffffu);
        csr16[row_start[d] + pv + pl] = (unsigned short)s;
    }
}

// ---------------------------------------------------------------------------
// LayerNorm -> bf16 packed pairs
// ---------------------------------------------------------------------------
__global__ __launch_bounds__(256) void ln_kernel(const float2* __restrict__ h2,
                                                 const float2* __restrict__ g2,
                                                 const float2* __restrict__ b2,
                                                 unsigned int* __restrict__ hnb) {
    int wid  = threadIdx.x >> 6;
    int lane = threadIdx.x & 63;
    int row  = blockIdx.x * 4 + wid;
    if (row >= N_NODES) return;
    float2 v = h2[(size_t)row * 64 + lane];
    float s  = v.x + v.y;
    float ss = v.x * v.x + v.y * v.y;
    #pragma unroll
    for (int off = 32; off; off >>= 1) {
        s  += __shfl_xor(s,  off, 64);
        ss += __shfl_xor(ss, off, 64);
    }
    float mu  = s * (1.0f / D);
    float var = ss * (1.0f / D) - mu * mu;
    float rs  = rsqrtf(var + EPS);
    float2 g = g2[lane], b = b2[lane];
    float y0 = (v.x - mu) * rs * g.x + b.x;
    float y1 = (v.y - mu) * rs * g.y + b.y;
    hnb[(size_t)row * 64 + lane] = (unsigned int)f2bf(y0) | ((unsigned int)f2bf(y1) << 16);
}

// ---------------------------------------------------------------------------
// aggregation: one wave per dst row; 4 x 16-lane groups process 4 edges
// concurrently, 16 B (8 features) per lane; cross-group shfl reduce at end.
// (round-6 proven configuration; csr indices now u16)
// ---------------------------------------------------------------------------
__global__ __launch_bounds__(256) void agg_kernel(const unsigned int* __restrict__ hnb,
                                                  const float* __restrict__ inv_out,
                                                  const float* __restrict__ inv_in,
                                                  const unsigned int* __restrict__ row_start,
                                                  const unsigned short* __restrict__ csr16,
                                                  unsigned int* __restrict__ aggb) {
    int wid  = threadIdx.x >> 6;
    int lane = threadIdx.x & 63;
    int row  = blockIdx.x * 4 + wid;
    if (row >= N_NODES) return;
    int g = lane >> 4, gl = lane & 15;
    unsigned int e0 = row_start[row], e1 = row_start[row + 1];
    float acc[8];
    #pragma unroll
    for (int j = 0; j < 8; ++j) acc[j] = 0.0f;

    unsigned int e = e0;
    while (e < e1) {
        unsigned int cnt = e1 - e;
        if (cnt > 64u) cnt = 64u;
        int sl = (lane < (int)cnt) ? (int)csr16[e + lane] : 0;
        int nit = ((int)cnt + 3) >> 2;
        for (int it = 0; it < nit; ++it) {
            int idx = it * 4 + g;
            int s = __shfl(sl, idx, 64);       // per-lane src (uniform in group)
            if (idx < (int)cnt) {
                float sc = inv_out[s];
                uint4 v = *(const uint4*)(hnb + (size_t)s * 64 + gl * 4);
                acc[0] = fmaf(__uint_as_float(v.x << 16),          sc, acc[0]);
                acc[1] = fmaf(__uint_as_float(v.x & 0xffff0000u),  sc, acc[1]);
                acc[2] = fmaf(__uint_as_float(v.y << 16),          sc, acc[2]);
                acc[3] = fmaf(__uint_as_float(v.y & 0xffff0000u),  sc, acc[3]);
                acc[4] = fmaf(__uint_as_float(v.z << 16),          sc, acc[4]);
                acc[5] = fmaf(__uint_as_float(v.z & 0xffff0000u),  sc, acc[5]);
                acc[6] = fmaf(__uint_as_float(v.w << 16),          sc, acc[6]);
                acc[7] = fmaf(__uint_as_float(v.w & 0xffff0000u),  sc, acc[7]);
            }
        }
        e += cnt;
    }
    // combine the 4 groups (lanes with equal gl)
    #pragma unroll
    for (int j = 0; j < 8; ++j) {
        acc[j] += __shfl_xor(acc[j], 16, 64);
        acc[j] += __shfl_xor(acc[j], 32, 64);
    }
    if (g == 0) {
        float ii = inv_in[row];
        uint4 o;
        o.x = (unsigned int)f2bf(acc[0] * ii) | ((unsigned int)f2bf(acc[1] * ii) << 16);
        o.y = (unsigned int)f2bf(acc[2] * ii) | ((unsigned int)f2bf(acc[3] * ii) << 16);
        o.z = (unsigned int)f2bf(acc[4] * ii) | ((unsigned int)f2bf(acc[5] * ii) << 16);
        o.w = (unsigned int)f2bf(acc[6] * ii) | ((unsigned int)f2bf(acc[7] * ii) << 16);
        *(uint4*)(aggb + (size_t)row * 64 + gl * 4) = o;
    }
}

// ---------------------------------------------------------------------------
// MFMA GEMM: out[50000][128] = cat([hn|agg]) @ W^T + b
// ---------------------------------------------------------------------------
__global__ __launch_bounds__(256) void gemm_kernel(const unsigned short* __restrict__ hnb,
                                                   const unsigned short* __restrict__ aggb,
                                                   const unsigned short* __restrict__ Wb,
                                                   const float* __restrict__ bias,
                                                   float* __restrict__ out) {
    __shared__ unsigned short wlds[128 * 264];
    int t = threadIdx.x;
    {
        int j = t >> 1, half = t & 1;
        const uint4* src = (const uint4*)(Wb + (size_t)j * 256 + half * 128);
        uint4* dst = (uint4*)(wlds + j * 264 + half * 128);
        #pragma unroll
        for (int i = 0; i < 16; ++i) dst[i] = src[i];
    }
    __syncthreads();

    int w = t >> 6, lane = t & 63;
    int rbase = blockIdx.x * 64 + w * 16;
    if (rbase >= N_NODES) return;
    int lrow = lane & 15, lhi = lane >> 4;

    bf16x8 a[8];
    const unsigned short* hrow = hnb + (size_t)(rbase + lrow) * 128 + lhi * 8;
    const unsigned short* arow = aggb + (size_t)(rbase + lrow) * 128 + lhi * 8;
    #pragma unroll
    for (int kc = 0; kc < 4; ++kc) a[kc]     = *(const bf16x8*)(hrow + kc * 32);
    #pragma unroll
    for (int kc = 0; kc < 4; ++kc) a[4 + kc] = *(const bf16x8*)(arow + kc * 32);

    f32x4 acc[8];
    #pragma unroll
    for (int ct = 0; ct < 8; ++ct) acc[ct] = (f32x4){0.f, 0.f, 0.f, 0.f};

    #pragma unroll
    for (int ct = 0; ct < 8; ++ct) {
        const unsigned short* bb = wlds + (ct * 16 + lrow) * 264 + lhi * 8;
        #pragma unroll
        for (int kc = 0; kc < 8; ++kc) {
            bf16x8 bfrag = *(const bf16x8*)(bb + kc * 32);
            acc[ct] = __builtin_amdgcn_mfma_f32_16x16x32_bf16(a[kc], bfrag, acc[ct], 0, 0, 0);
        }
    }

    #pragma unroll
    for (int ct = 0; ct < 8; ++ct) {
        int col = ct * 16 + lrow;
        float bv = bias[col];
        #pragma unroll
        for (int i = 0; i < 4; ++i) {
            int row = rbase + lhi * 4 + i;
            out[(size_t)row * 128 + col] = acc[ct][i] + bv;
        }
    }
}

// ---------------------------------------------------------------------------
extern "C" void kernel_launch(void* const* d_in, const int* in_sizes, int n_in,
                              void* d_out, int out_size, void* d_ws, size_t ws_size,
                              hipStream_t stream) {
    const float* h     = (const float*)d_in[0];
    const unsigned int* eraw = (const unsigned int*)d_in[1];
    const float* gamma = (const float*)d_in[2];
    const float* beta  = (const float*)d_in[3];
    const float* W     = (const float*)d_in[4];
    const float* bias  = (const float*)d_in[5];
    float* out = (float*)d_out;

    char* ws = (char*)d_ws;
    size_t off = 0;
    auto alloc = [&](size_t bytes) { size_t o = off; off += (bytes + 255) & ~(size_t)255; return o; };
    unsigned int*  hpart     = (unsigned int*)(ws + alloc((size_t)2 * HG * NWORDS * 4)); // 25.6 MB
    unsigned int*  pre16     = (unsigned int*)(ws + alloc((size_t)HG * NWORDS * 4));     // 12.8 MB
    unsigned int*  deg_in    = (unsigned int*)(ws + alloc((size_t)N_NODES * 4));
    float*         inv_out   = (float*)(ws + alloc((size_t)N_NODES * 4));
    float*         inv_in    = (float*)(ws + alloc((size_t)N_NODES * 4));
    unsigned int*  row_start = (unsigned int*)(ws + alloc((size_t)(N_NODES + 1) * 4));
    unsigned int*  spart     = (unsigned int*)(ws + alloc(64 * 4));
    unsigned int*  Wb        = (unsigned int*)(ws + alloc((size_t)128 * 256 * 2));
    unsigned short* csr16    = (unsigned short*)(ws + alloc((size_t)N_EDGES * 2));
    unsigned int*  hnb       = (unsigned int*)(ws + alloc((size_t)N_NODES * D * 2));
    unsigned int*  aggb      = (unsigned int*)(ws + alloc((size_t)N_NODES * D * 2));

    hist_kernel<<<2 * HG, 1024, 0, stream>>>(eraw, hpart, (const float2*)W, Wb);
    ln_kernel<<<(N_NODES + 3) / 4, 256, 0, stream>>>((const float2*)h, (const float2*)gamma,
                                                     (const float2*)beta, hnb);
    reduce_prefix<<<(NWORDS + 255) / 256, 256, 0, stream>>>(hpart, deg_in, inv_out,
                                                            inv_in, pre16);
    scan1<<<(N_NODES + 1023) / 1024, 1024, 0, stream>>>(deg_in, row_start, spart);
    scan2<<<(N_NODES + 1023) / 1024, 1024, 0, stream>>>(spart, row_start);
    fill_kernel<<<HG, 1024, 0, stream>>>(eraw, pre16, row_start, csr16);
    agg_kernel<<<(N_NODES + 3) / 4, 256, 0, stream>>>(hnb, inv_out, inv_in, row_start,
                                                      csr16, aggb);
    gemm_kernel<<<(N_NODES + 63) / 64, 256, 0, stream>>>((const unsigned short*)hnb,
                                                         (const unsigned short*)aggb,
                                                         (const unsigned short*)Wb,
                                                         bias, out);
}